// Round 1
// baseline (4502.667 us; speedup 1.0000x reference)
//
#include <hip/hip_runtime.h>
#include <math.h>

// Problem constants
#define BATCH  16384
#define HID    4096
#define NCOLS  1536     // NUM_SUB * H * 2
#define NGRP   384      // NUM_SUB * H / RANK

// Gap threshold: fp32-path score error vs fp64 is ~2e-6 worst case (dominated
// by fp32 exp/log, not the GEMM); bf16x3 adds ~2e-7. 3e-5 keeps >10x margin.
#define GAP_MIN 3.0e-5f

typedef unsigned short u16;
typedef short bf16x8 __attribute__((ext_vector_type(8)));
typedef float f32x4  __attribute__((ext_vector_type(4)));

__device__ __forceinline__ int budget_of(float lat) {
    float un = rintf(lat * 512.0f);           // round-half-even like jnp.round
    un = fminf(fmaxf(un, 128.0f), 512.0f);
    return (int)un - 128;                     // 0..384
}

__device__ __forceinline__ double gumbel_d(float uu) {
    double v = (double)uu * (1.0 - 2.0e-6) + 1.0e-6;
    return -log(-log(v));
}

// fp32 gumbel, accurate at BOTH tails.
__device__ __forceinline__ float gumbel_f(float u) {
    float inner;
    if (u <= 0.5f) {
        float v = fmaf(u, 0.999998f, 1e-6f);          // u*(1-2e-6)+1e-6
        inner = -logf(v);
    } else {
        float t1 = 1.0f - u;                          // exact
        float w  = fmaf(1e-6f, fmaf(2.0f, u, -1.0f), t1);
        inner = -log1pf(-w);
    }
    return -logf(inner);
}

__device__ __forceinline__ float score_f(float l0, float l1, float l2, float l3,
                                         float4 uv) {
    const float d0 = ((l0 + gumbel_f(uv.x)) - (l1 + gumbel_f(uv.y))) * 0.2f;
    const float d1 = ((l2 + gumbel_f(uv.z)) - (l3 + gumbel_f(uv.w))) * 0.2f;
    const float p0 = 1.0f / (1.0f + expf(-d0));
    const float p1 = 1.0f / (1.0f + expf(-d1));
    return 0.5f * (p0 + p1);
}

// ---- bf16 split helpers ----
__device__ __forceinline__ unsigned bf16_rne_bits(float f) {
    unsigned b = __float_as_uint(f);
    return (b + 0x7FFFu + ((b >> 16) & 1u)) >> 16;
}

// Hot-path split: hi = RTZ-bf16 (bitmask), lo = RNE-bf16(x - hi).
// Residual <= 2^-17|x|; contributes ~1e-7 score error. Packs pairs into u32.
__device__ __forceinline__ void split4(const float4 v, uint2& hi, uint2& lo) {
    const unsigned bx = __float_as_uint(v.x), by = __float_as_uint(v.y),
                   bz = __float_as_uint(v.z), bw = __float_as_uint(v.w);
    const unsigned hx = bx & 0xFFFF0000u, hy = by & 0xFFFF0000u,
                   hz = bz & 0xFFFF0000u, hw = bw & 0xFFFF0000u;
    hi.x = (hx >> 16) | hy;
    hi.y = (hz >> 16) | hw;
    const float lx = v.x - __uint_as_float(hx);
    const float ly = v.y - __uint_as_float(hy);
    const float lz = v.z - __uint_as_float(hz);
    const float lw = v.w - __uint_as_float(hw);
    lo.x = bf16_rne_bits(lx) | (bf16_rne_bits(ly) << 16);
    lo.y = bf16_rne_bits(lz) | (bf16_rne_bits(lw) << 16);
}

// Per-sample classification + trivial-output fill + compaction of interior rows.
__global__ __launch_bounds__(64)
void prefilter_kernel(const float* __restrict__ latency, float* __restrict__ out,
                      int* __restrict__ count, int* __restrict__ idx)
{
    const int b = blockIdx.x;
    const int t = threadIdx.x;
    const int budget = budget_of(latency[b]);
    float* obase = out + (size_t)b * 2048;

    const float4 ones = make_float4(1.f, 1.f, 1.f, 1.f);
    ((float4*)obase)[t]      = ones;   // prefix: layers 0..7 all ones
    ((float4*)obase)[t + 64] = ones;

    if (budget > 0 && budget < NGRP) {
        if (t == 0) { int s = atomicAdd(count, 1); idx[s] = b; }
    } else {
        const float K = (budget == 0) ? 0.0f : 1.0f;
#pragma unroll
        for (int j = 0; j < 6; ++j) {
            const int i = j * 64 + t;
            const int p = i * 4;             // p = l*64 + s*32 + h
            const int s = (p >> 5) & 1;
            const float v = s ? (1.0f - K) : K;
            ((float4*)(obase + 512))[i] = make_float4(v, v, v, v);
        }
    }
}

// One-time W transpose + bf16 hi/lo split: W[k][n] fp32 -> WT_hi/WT_lo [n][k] bf16.
__global__ __launch_bounds__(256)
void convert_w(const float* __restrict__ W, u16* __restrict__ wt_hi,
               u16* __restrict__ wt_lo)
{
    __shared__ float sT[32][33];
    const int n0 = blockIdx.x * 32, k0 = blockIdx.y * 32;
    const int t  = threadIdx.x;
    {
        const int lr = t >> 3, lc = (t & 7) * 4;
        const float4 v = *(const float4*)(W + (size_t)(k0 + lr) * NCOLS + n0 + lc);
        sT[lr][lc] = v.x; sT[lr][lc + 1] = v.y; sT[lr][lc + 2] = v.z; sT[lr][lc + 3] = v.w;
    }
    __syncthreads();
    const int ln = t >> 3, lk = (t & 7) * 4;
    unsigned hb[4], lb[4];
#pragma unroll
    for (int j = 0; j < 4; ++j) {
        const float xv = sT[lk + j][ln];
        const unsigned h = bf16_rne_bits(xv);          // RNE hi for W (one-time)
        const float hf = __uint_as_float(h << 16);
        hb[j] = h;
        lb[j] = bf16_rne_bits(xv - hf);
    }
    uint2 hw, lw;
    hw.x = hb[0] | (hb[1] << 16); hw.y = hb[2] | (hb[3] << 16);
    lw.x = lb[0] | (lb[1] << 16); lw.y = lb[2] | (lb[3] << 16);
    const size_t off = (size_t)(n0 + ln) * HID + k0 + lk;
    *(uint2*)(wt_hi + off) = hw;
    *(uint2*)(wt_lo + off) = lw;
}

// bf16x3 MFMA GEMM (128x128 tile, BK=32) + fp32 gumbel-softmax scores.
// acc = x_hi@w_hi + x_hi@w_lo + x_lo@w_hi, fp32 accumulation on matrix cores.
__global__ __launch_bounds__(256)
void gemm_bf16x3(const float* __restrict__ x, const u16* __restrict__ wt_hi,
                 const u16* __restrict__ wt_lo, const float* __restrict__ bias,
                 const float* __restrict__ uu, const int* __restrict__ idx,
                 const int* __restrict__ count, float* __restrict__ scoresf)
{
    // 4 planes of [128 rows][40 bf16] (32 k + 8 pad -> 80B rows, 2-way banks max)
    __shared__ u16 sMem[4 * 128 * 40];
    __shared__ int rid[128];
    u16* const sAh = sMem;
    u16* const sAl = sMem + 5120;
    u16* const sBh = sMem + 10240;
    u16* const sBl = sMem + 15360;

    const int cnt  = *count;
    const int row0 = blockIdx.y * 128;
    if (row0 >= cnt) return;
    const int col0 = blockIdx.x * 128;
    const int t    = threadIdx.x;

    if (t < 128) rid[t] = idx[min(row0 + t, cnt - 1)];
    __syncthreads();

    // ---- staging maps ----
    const int ar  = t >> 2;             // A rows ar and ar+64
    const int akc = (t & 3) << 3;       // k offset {0,8,16,24}
    const int arow  = ar * 40 + akc;
    const int arow2 = (ar + 64) * 40 + akc;
    const size_t xoff0 = (size_t)rid[ar] * HID + akc;
    const size_t xoff1 = (size_t)rid[ar + 64] * HID + akc;

    const int bn = t >> 1;              // B row (n) 0..127
    const int bk = (t & 1) << 4;        // k offset {0,16}
    const int brow = bn * 40 + bk;
    const u16* const whp = wt_hi + (size_t)(col0 + bn) * HID + bk;
    const u16* const wlp = wt_lo + (size_t)(col0 + bn) * HID + bk;

    // ---- fragment maps ----
    const int lane = t & 63;
    const int wave = t >> 6;
    const int wr = wave >> 1;           // wave row half
    const int wc = wave & 1;            // wave col half
    const int fr = lane & 15;
    const int kb = lane >> 4;           // 0..3
    const int abase = (wr * 64 + fr) * 40 + kb * 8;
    const int bbase = (wc * 64 + fr) * 40 + kb * 8;

    f32x4 acc[4][4] = {};

    // prefetch tile 0
    float4 a00 = *(const float4*)(x + xoff0);
    float4 a01 = *(const float4*)(x + xoff0 + 4);
    float4 a10 = *(const float4*)(x + xoff1);
    float4 a11 = *(const float4*)(x + xoff1 + 4);
    uint4 pb0 = *(const uint4*)(whp);
    uint4 pb1 = *(const uint4*)(whp + 8);
    uint4 pb2 = *(const uint4*)(wlp);
    uint4 pb3 = *(const uint4*)(wlp + 8);

#pragma unroll 1
    for (int k0 = 0; k0 < HID; k0 += 32) {
        __syncthreads();
        {   // A: convert fp32 -> bf16 hi/lo, write LDS
            uint2 h, l;
            split4(a00, h, l); *(uint2*)&sAh[arow]      = h; *(uint2*)&sAl[arow]      = l;
            split4(a01, h, l); *(uint2*)&sAh[arow + 4]  = h; *(uint2*)&sAl[arow + 4]  = l;
            split4(a10, h, l); *(uint2*)&sAh[arow2]     = h; *(uint2*)&sAl[arow2]     = l;
            split4(a11, h, l); *(uint2*)&sAh[arow2 + 4] = h; *(uint2*)&sAl[arow2 + 4] = l;
            // B: already bf16, straight copy
            *(uint4*)&sBh[brow]     = pb0; *(uint4*)&sBh[brow + 8] = pb1;
            *(uint4*)&sBl[brow]     = pb2; *(uint4*)&sBl[brow + 8] = pb3;
        }
        __syncthreads();

        if (k0 + 32 < HID) {
            a00 = *(const float4*)(x + xoff0 + k0 + 32);
            a01 = *(const float4*)(x + xoff0 + k0 + 36);
            a10 = *(const float4*)(x + xoff1 + k0 + 32);
            a11 = *(const float4*)(x + xoff1 + k0 + 36);
            pb0 = *(const uint4*)(whp + k0 + 32);
            pb1 = *(const uint4*)(whp + k0 + 40);
            pb2 = *(const uint4*)(wlp + k0 + 32);
            pb3 = *(const uint4*)(wlp + k0 + 40);
        }

        bf16x8 bh[4], bl[4];
#pragma unroll
        for (int ni = 0; ni < 4; ++ni) {
            bh[ni] = *(const bf16x8*)&sBh[bbase + ni * 640];
            bl[ni] = *(const bf16x8*)&sBl[bbase + ni * 640];
        }
#pragma unroll
        for (int mi = 0; mi < 4; ++mi) {
            const bf16x8 ah = *(const bf16x8*)&sAh[abase + mi * 640];
            const bf16x8 al = *(const bf16x8*)&sAl[abase + mi * 640];
#pragma unroll
            for (int ni = 0; ni < 4; ++ni) {
                acc[mi][ni] = __builtin_amdgcn_mfma_f32_16x16x32_bf16(ah, bh[ni], acc[mi][ni], 0, 0, 0);
                acc[mi][ni] = __builtin_amdgcn_mfma_f32_16x16x32_bf16(ah, bl[ni], acc[mi][ni], 0, 0, 0);
                acc[mi][ni] = __builtin_amdgcn_mfma_f32_16x16x32_bf16(al, bh[ni], acc[mi][ni], 0, 0, 0);
            }
        }
    }

    // ---- epilogue: LDS transpose of MFMA layout, then scores ----
    // MFMA D layout: col = lane&15, row = 4*(lane>>4)+r  (per frag)
    float* const sOut = (float*)sMem;                  // 4 waves x [16][68] f32
    float* const sW   = sOut + wave * (16 * 68);
    const int gb = (col0 >> 2) + wc * 16;              // global group base (wave)

#pragma unroll 1
    for (int mi = 0; mi < 4; ++mi) {
        __syncthreads();
#pragma unroll
        for (int ni = 0; ni < 4; ++ni)
#pragma unroll
            for (int r = 0; r < 4; ++r)
                sW[(kb * 4 + r) * 68 + ni * 16 + fr] = acc[mi][ni][r];
        __syncthreads();

        const int lr    = fr;                          // row 0..15
        const int gq    = kb;                          // group quad 0..3
        const int row_l = wr * 64 + mi * 16 + lr;      // local compact row
        const int cr    = row0 + row_l;
        const int orig  = rid[row_l];
        const float* so = sW + lr * 68 + gq * 16;
        const int g0    = gb + gq * 4;

        float s[4];
#pragma unroll
        for (int j = 0; j < 4; ++j) {
            const int g = g0 + j;
            const float4 lv = *(const float4*)(so + 4 * j);
            const float4 bv = *(const float4*)(bias + 4 * g);
            const float4 uv = *(const float4*)(uu + (size_t)orig * NCOLS + 4 * g);
            s[j] = score_f(lv.x + bv.x, lv.y + bv.y, lv.z + bv.z, lv.w + bv.w, uv);
        }
        *(float4*)&scoresf[(size_t)cr * NGRP + g0] = make_float4(s[0], s[1], s[2], s[3]);
    }
}

// fp32 selection with boundary-gap certification; flags close calls for fp64.
__global__ __launch_bounds__(384)
void select_fast(const float* __restrict__ scoresf, const float* __restrict__ latency,
                 const int* __restrict__ idx, const int* __restrict__ count,
                 float* __restrict__ out, int* __restrict__ ridx, int* __restrict__ rcount)
{
    const int b = blockIdx.x;
    if (b >= *count) return;
    const int t = threadIdx.x;
    const int orig = idx[b];

    __shared__ float sm[NGRP];
    __shared__ float bnd[2];
    __shared__ int   flag;
    const float sg = scoresf[(size_t)b * NGRP + t];
    sm[t] = sg;
    if (t == 0) flag = 0;
    const int budget = budget_of(latency[orig]);   // 1..383 here
    __syncthreads();

    int rank = 0;
#pragma unroll 8
    for (int j = 0; j < NGRP; ++j) {
        const float sj = sm[j];
        rank += (sj > sg || (sj == sg && j < t)) ? 1 : 0;
    }
    if (rank == budget - 1) bnd[0] = sg;   // min of kept set
    if (rank == budget)     bnd[1] = sg;   // max of dropped set
    __syncthreads();
    if (t == 0 && (bnd[0] - bnd[1] < GAP_MIN)) {
        flag = 1;
        ridx[atomicAdd(rcount, 1)] = orig;
    }
    __syncthreads();
    if (flag) return;

    const float keep = (rank < budget) ? 1.0f : 0.0f;
    float* p = out + (size_t)orig * 2048 + 512 + (size_t)(t >> 4) * 64;
    const int h2 = (t & 15) << 1;
    *(float2*)(p + h2)      = make_float2(keep, keep);
    *(float2*)(p + 32 + h2) = make_float2(1.0f - keep, 1.0f - keep);
}

// fp64 repair GEMM over flagged rows only. BM=32 for block-level parallelism.
__global__ __launch_bounds__(256)
void gemm64_repair(const float* __restrict__ x, const float* __restrict__ W,
                   const float* __restrict__ bias, const float* __restrict__ u,
                   const int* __restrict__ ridx, const int* __restrict__ rcount,
                   double* __restrict__ scores)
{
    __shared__ float As[16][36];
    __shared__ float Bs[16][68];
    __shared__ int   rid[32];

    const int cnt  = *rcount;
    const int row0 = blockIdx.y * 32;
    if (row0 >= cnt) return;
    const int col0 = blockIdx.x * 64;
    const int t    = threadIdx.x;

    if (t < 32) rid[t] = ridx[min(row0 + t, cnt - 1)];
    __syncthreads();

    const bool doA = (t < 128);
    const int ar  = t >> 2;            // 0..31 when doA
    const int akc = (t & 3) << 2;
    const int bkr = t >> 4;
    const int bnc = (t & 15) << 2;

    size_t xoff = 0;
    if (doA) xoff = (size_t)rid[ar] * HID + akc;
    const float* wp = W + (size_t)bkr * NCOLS + col0 + bnc;

    const int ty = t >> 4;             // rows 2ty, 2ty+1
    const int tx = t & 15;

    double acc[2][4] = {};

    float4 a0 = make_float4(0, 0, 0, 0);
    if (doA) a0 = *(const float4*)(x + xoff);
    float4 b0 = *(const float4*)(wp);

    for (int k0 = 0; k0 < HID; k0 += 16) {
        __syncthreads();
        if (doA) {
            As[akc + 0][ar] = a0.x; As[akc + 1][ar] = a0.y;
            As[akc + 2][ar] = a0.z; As[akc + 3][ar] = a0.w;
        }
        *(float4*)&Bs[bkr][bnc] = b0;
        __syncthreads();
        if (k0 + 16 < HID) {
            if (doA) a0 = *(const float4*)(x + xoff + k0 + 16);
            b0 = *(const float4*)(wp + (size_t)(k0 + 16) * NCOLS);
        }
#pragma unroll
        for (int k = 0; k < 16; ++k) {
            const double a0d = (double)As[k][ty * 2];
            const double a1d = (double)As[k][ty * 2 + 1];
            const float4 bf  = *(const float4*)&Bs[k][tx * 4];
            const double bd[4] = {(double)bf.x, (double)bf.y, (double)bf.z, (double)bf.w};
#pragma unroll
            for (int j = 0; j < 4; ++j) {
                acc[0][j] = fma(a0d, bd[j], acc[0][j]);
                acc[1][j] = fma(a1d, bd[j], acc[1][j]);
            }
        }
    }

    const int g = (col0 >> 2) + tx;
    const double bs0 = (double)bias[4 * g + 0];
    const double bs1 = (double)bias[4 * g + 1];
    const double bs2 = (double)bias[4 * g + 2];
    const double bs3 = (double)bias[4 * g + 3];
#pragma unroll
    for (int i = 0; i < 2; ++i) {
        const int rl   = ty * 2 + i;
        const int cr   = row0 + rl;
        const int orig = rid[rl];
        const float4 uv = *(const float4*)(u + (size_t)orig * NCOLS + 4 * g);
        const double l0 = acc[i][0] + bs0;
        const double l1 = acc[i][1] + bs1;
        const double l2 = acc[i][2] + bs2;
        const double l3 = acc[i][3] + bs3;
        const double d0 = ((l0 + gumbel_d(uv.x)) - (l1 + gumbel_d(uv.y))) / 5.0;
        const double d1 = ((l2 + gumbel_d(uv.z)) - (l3 + gumbel_d(uv.w))) / 5.0;
        const double p0 = 1.0 / (1.0 + exp(-d0));
        const double p1 = 1.0 / (1.0 + exp(-d1));
        scores[(size_t)cr * NGRP + g] = 0.5 * (p0 + p1);
    }
}

// fp64 selection for flagged rows (no gap test).
__global__ __launch_bounds__(384)
void select_repair(const double* __restrict__ scores, const float* __restrict__ latency,
                   const int* __restrict__ ridx, const int* __restrict__ rcount,
                   float* __restrict__ out)
{
    const int b = blockIdx.x;
    if (b >= *rcount) return;
    const int t = threadIdx.x;
    const int orig = ridx[b];

    __shared__ double sm[NGRP];
    const double sg = scores[(size_t)b * NGRP + t];
    sm[t] = sg;
    const int budget = budget_of(latency[orig]);
    __syncthreads();

    int rank = 0;
#pragma unroll 8
    for (int j = 0; j < NGRP; ++j) {
        const double sj = sm[j];
        rank += (sj > sg || (sj == sg && j < t)) ? 1 : 0;
    }
    const float keep = (rank < budget) ? 1.0f : 0.0f;

    float* p = out + (size_t)orig * 2048 + 512 + (size_t)(t >> 4) * 64;
    const int h2 = (t & 15) << 1;
    *(float2*)(p + h2)      = make_float2(keep, keep);
    *(float2*)(p + 32 + h2) = make_float2(1.0f - keep, 1.0f - keep);
}

extern "C" void kernel_launch(void* const* d_in, const int* in_sizes, int n_in,
                              void* d_out, int out_size, void* d_ws, size_t ws_size,
                              hipStream_t stream) {
    const float* x       = (const float*)d_in[0];
    const float* latency = (const float*)d_in[1];
    const float* W       = (const float*)d_in[2];
    const float* bias    = (const float*)d_in[3];
    const float* u       = (const float*)d_in[4];
    float* out           = (float*)d_out;

    // ws layout (total 50,462,976 B — identical footprint to previous version):
    //   [count,rcount.. 256B][idx 64KB][ridx 64KB]
    //   [WT_hi 12.58MB][WT_lo 12.58MB][scoresf 25.17MB]
    //   scores64 (fp64, 50.33MB) ALIASES [WT_hi..scoresf]: WT planes are dead
    //   after gemm_bf16x3, scoresf is dead after select_fast, and gemm64_repair
    //   (which writes scores64) runs after select_fast. Lifetimes disjoint.
    int*    count   = (int*)d_ws;
    int*    rcount  = (int*)((char*)d_ws + 4);
    int*    idx     = (int*)((char*)d_ws + 256);
    int*    ridx    = (int*)((char*)d_ws + 256 + 65536);
    u16*    wt_hi   = (u16*)((char*)d_ws + 131328);
    u16*    wt_lo   = (u16*)((char*)d_ws + 131328 + 12582912);
    float*  scoresf = (float*)((char*)d_ws + 131328 + 25165824);
    double* scores64= (double*)((char*)d_ws + 131328);

    hipMemsetAsync(d_ws, 0, 256, stream);
    convert_w<<<dim3(NCOLS / 32, HID / 32), 256, 0, stream>>>(W, wt_hi, wt_lo);
    prefilter_kernel<<<BATCH, 64, 0, stream>>>(latency, out, count, idx);
    gemm_bf16x3<<<dim3(NCOLS / 128, BATCH / 128), 256, 0, stream>>>(
        x, wt_hi, wt_lo, bias, u, idx, count, scoresf);
    select_fast<<<BATCH, NGRP, 0, stream>>>(scoresf, latency, idx, count, out, ridx, rcount);
    gemm64_repair<<<dim3(NCOLS / 64, BATCH / 32), 256, 0, stream>>>(
        x, W, bias, u, ridx, rcount, scores64);
    select_repair<<<BATCH, NGRP, 0, stream>>>(scores64, latency, ridx, rcount, out);
}

// Round 2
// 1655.659 us; speedup vs baseline: 2.7196x; 2.7196x over previous
//
#include <hip/hip_runtime.h>
#include <math.h>

// Problem constants
#define BATCH  16384
#define HID    4096
#define NCOLS  1536     // NUM_SUB * H * 2
#define NGRP   384      // NUM_SUB * H / RANK

// Gap threshold: fp32-path score error vs fp64 is ~2e-6 worst case (dominated
// by fp32 exp/log, not the GEMM); bf16x3 adds ~2e-7. 3e-5 keeps >10x margin.
#define GAP_MIN 3.0e-5f

typedef unsigned short u16;
typedef short bf16x8 __attribute__((ext_vector_type(8)));
typedef float f32x4  __attribute__((ext_vector_type(4)));

__device__ __forceinline__ int budget_of(float lat) {
    float un = rintf(lat * 512.0f);           // round-half-even like jnp.round
    un = fminf(fmaxf(un, 128.0f), 512.0f);
    return (int)un - 128;                     // 0..384
}

__device__ __forceinline__ double gumbel_d(float uu) {
    double v = (double)uu * (1.0 - 2.0e-6) + 1.0e-6;
    return -log(-log(v));
}

// fp32 gumbel, accurate at BOTH tails.
__device__ __forceinline__ float gumbel_f(float u) {
    float inner;
    if (u <= 0.5f) {
        float v = fmaf(u, 0.999998f, 1e-6f);          // u*(1-2e-6)+1e-6
        inner = -logf(v);
    } else {
        float t1 = 1.0f - u;                          // exact
        float w  = fmaf(1e-6f, fmaf(2.0f, u, -1.0f), t1);
        inner = -log1pf(-w);
    }
    return -logf(inner);
}

__device__ __forceinline__ float score_f(float l0, float l1, float l2, float l3,
                                         float4 uv) {
    const float d0 = ((l0 + gumbel_f(uv.x)) - (l1 + gumbel_f(uv.y))) * 0.2f;
    const float d1 = ((l2 + gumbel_f(uv.z)) - (l3 + gumbel_f(uv.w))) * 0.2f;
    const float p0 = 1.0f / (1.0f + expf(-d0));
    const float p1 = 1.0f / (1.0f + expf(-d1));
    return 0.5f * (p0 + p1);
}

// ---- bf16 split helpers ----
__device__ __forceinline__ unsigned bf16_rne_bits(float f) {
    unsigned b = __float_as_uint(f);
    return (b + 0x7FFFu + ((b >> 16) & 1u)) >> 16;
}

// Hot-path split: hi = RTZ-bf16 (bitmask), lo = RNE-bf16(x - hi).
// Residual <= 2^-17|x|; contributes ~1e-7 score error. Packs pairs into u32.
__device__ __forceinline__ void split4(const float4 v, uint2& hi, uint2& lo) {
    const unsigned bx = __float_as_uint(v.x), by = __float_as_uint(v.y),
                   bz = __float_as_uint(v.z), bw = __float_as_uint(v.w);
    const unsigned hx = bx & 0xFFFF0000u, hy = by & 0xFFFF0000u,
                   hz = bz & 0xFFFF0000u, hw = bw & 0xFFFF0000u;
    hi.x = (hx >> 16) | hy;
    hi.y = (hz >> 16) | hw;
    const float lx = v.x - __uint_as_float(hx);
    const float ly = v.y - __uint_as_float(hy);
    const float lz = v.z - __uint_as_float(hz);
    const float lw = v.w - __uint_as_float(hw);
    lo.x = bf16_rne_bits(lx) | (bf16_rne_bits(ly) << 16);
    lo.y = bf16_rne_bits(lz) | (bf16_rne_bits(lw) << 16);
}

// Per-sample classification + trivial-output fill + compaction of interior rows.
__global__ __launch_bounds__(64)
void prefilter_kernel(const float* __restrict__ latency, float* __restrict__ out,
                      int* __restrict__ count, int* __restrict__ idx)
{
    const int b = blockIdx.x;
    const int t = threadIdx.x;
    const int budget = budget_of(latency[b]);
    float* obase = out + (size_t)b * 2048;

    const float4 ones = make_float4(1.f, 1.f, 1.f, 1.f);
    ((float4*)obase)[t]      = ones;   // prefix: layers 0..7 all ones
    ((float4*)obase)[t + 64] = ones;

    if (budget > 0 && budget < NGRP) {
        if (t == 0) { int s = atomicAdd(count, 1); idx[s] = b; }
    } else {
        const float K = (budget == 0) ? 0.0f : 1.0f;
#pragma unroll
        for (int j = 0; j < 6; ++j) {
            const int i = j * 64 + t;
            const int p = i * 4;             // p = l*64 + s*32 + h
            const int s = (p >> 5) & 1;
            const float v = s ? (1.0f - K) : K;
            ((float4*)(obase + 512))[i] = make_float4(v, v, v, v);
        }
    }
}

// One-time W transpose + bf16 hi/lo split: W[k][n] fp32 -> WT_hi/WT_lo [n][k] bf16.
__global__ __launch_bounds__(256)
void convert_w(const float* __restrict__ W, u16* __restrict__ wt_hi,
               u16* __restrict__ wt_lo)
{
    __shared__ float sT[32][33];
    const int n0 = blockIdx.x * 32, k0 = blockIdx.y * 32;
    const int t  = threadIdx.x;
    {
        const int lr = t >> 3, lc = (t & 7) * 4;
        const float4 v = *(const float4*)(W + (size_t)(k0 + lr) * NCOLS + n0 + lc);
        sT[lr][lc] = v.x; sT[lr][lc + 1] = v.y; sT[lr][lc + 2] = v.z; sT[lr][lc + 3] = v.w;
    }
    __syncthreads();
    const int ln = t >> 3, lk = (t & 7) * 4;
    unsigned hb[4], lb[4];
#pragma unroll
    for (int j = 0; j < 4; ++j) {
        const float xv = sT[lk + j][ln];
        const unsigned h = bf16_rne_bits(xv);          // RNE hi for W (one-time)
        const float hf = __uint_as_float(h << 16);
        hb[j] = h;
        lb[j] = bf16_rne_bits(xv - hf);
    }
    uint2 hw, lw;
    hw.x = hb[0] | (hb[1] << 16); hw.y = hb[2] | (hb[3] << 16);
    lw.x = lb[0] | (lb[1] << 16); lw.y = lb[2] | (lb[3] << 16);
    const size_t off = (size_t)(n0 + ln) * HID + k0 + lk;
    *(uint2*)(wt_hi + off) = hw;
    *(uint2*)(wt_lo + off) = lw;
}

// bf16x3 MFMA GEMM (128x128 tile, BK=32) + fp32 gumbel-softmax scores.
// acc = x_hi@w_hi + x_hi@w_lo + x_lo@w_hi, fp32 accumulation on matrix cores.
// NOTE: every access to acc[][] must be compile-time-indexed (full unroll) —
// a single runtime index demotes the whole array to scratch (r1 post-mortem:
// 14.6 GB HBM scratch traffic, VGPR=68, 3605 us).
__global__ __launch_bounds__(256)
void gemm_bf16x3(const float* __restrict__ x, const u16* __restrict__ wt_hi,
                 const u16* __restrict__ wt_lo, const float* __restrict__ bias,
                 const float* __restrict__ uu, const int* __restrict__ idx,
                 const int* __restrict__ count, float* __restrict__ scoresf)
{
    // 4 planes of [128 rows][40 bf16] (32 k + 8 pad -> 80B rows, 2-way banks max)
    __shared__ u16 sMem[4 * 128 * 40];
    __shared__ int rid[128];
    u16* const sAh = sMem;
    u16* const sAl = sMem + 5120;
    u16* const sBh = sMem + 10240;
    u16* const sBl = sMem + 15360;

    const int cnt  = *count;
    const int row0 = blockIdx.y * 128;
    if (row0 >= cnt) return;
    const int col0 = blockIdx.x * 128;
    const int t    = threadIdx.x;

    if (t < 128) rid[t] = idx[min(row0 + t, cnt - 1)];
    __syncthreads();

    // ---- staging maps ----
    const int ar  = t >> 2;             // A rows ar and ar+64
    const int akc = (t & 3) << 3;       // k offset {0,8,16,24}
    const int arow  = ar * 40 + akc;
    const int arow2 = (ar + 64) * 40 + akc;
    const size_t xoff0 = (size_t)rid[ar] * HID + akc;
    const size_t xoff1 = (size_t)rid[ar + 64] * HID + akc;

    const int bn = t >> 1;              // B row (n) 0..127
    const int bk = (t & 1) << 4;        // k offset {0,16}
    const int brow = bn * 40 + bk;
    const u16* const whp = wt_hi + (size_t)(col0 + bn) * HID + bk;
    const u16* const wlp = wt_lo + (size_t)(col0 + bn) * HID + bk;

    // ---- fragment maps ----
    const int lane = t & 63;
    const int wave = t >> 6;
    const int wr = wave >> 1;           // wave row half
    const int wc = wave & 1;            // wave col half
    const int fr = lane & 15;
    const int kb = lane >> 4;           // 0..3
    const int abase = (wr * 64 + fr) * 40 + kb * 8;
    const int bbase = (wc * 64 + fr) * 40 + kb * 8;

    f32x4 acc[4][4] = {};

    // prefetch tile 0
    float4 a00 = *(const float4*)(x + xoff0);
    float4 a01 = *(const float4*)(x + xoff0 + 4);
    float4 a10 = *(const float4*)(x + xoff1);
    float4 a11 = *(const float4*)(x + xoff1 + 4);
    uint4 pb0 = *(const uint4*)(whp);
    uint4 pb1 = *(const uint4*)(whp + 8);
    uint4 pb2 = *(const uint4*)(wlp);
    uint4 pb3 = *(const uint4*)(wlp + 8);

#pragma unroll 1
    for (int k0 = 0; k0 < HID; k0 += 32) {
        __syncthreads();
        {   // A: convert fp32 -> bf16 hi/lo, write LDS
            uint2 h, l;
            split4(a00, h, l); *(uint2*)&sAh[arow]      = h; *(uint2*)&sAl[arow]      = l;
            split4(a01, h, l); *(uint2*)&sAh[arow + 4]  = h; *(uint2*)&sAl[arow + 4]  = l;
            split4(a10, h, l); *(uint2*)&sAh[arow2]     = h; *(uint2*)&sAl[arow2]     = l;
            split4(a11, h, l); *(uint2*)&sAh[arow2 + 4] = h; *(uint2*)&sAl[arow2 + 4] = l;
            // B: already bf16, straight copy
            *(uint4*)&sBh[brow]     = pb0; *(uint4*)&sBh[brow + 8] = pb1;
            *(uint4*)&sBl[brow]     = pb2; *(uint4*)&sBl[brow + 8] = pb3;
        }
        __syncthreads();

        if (k0 + 32 < HID) {
            a00 = *(const float4*)(x + xoff0 + k0 + 32);
            a01 = *(const float4*)(x + xoff0 + k0 + 36);
            a10 = *(const float4*)(x + xoff1 + k0 + 32);
            a11 = *(const float4*)(x + xoff1 + k0 + 36);
            pb0 = *(const uint4*)(whp + k0 + 32);
            pb1 = *(const uint4*)(whp + k0 + 40);
            pb2 = *(const uint4*)(wlp + k0 + 32);
            pb3 = *(const uint4*)(wlp + k0 + 40);
        }

        bf16x8 bh[4], bl[4];
#pragma unroll
        for (int ni = 0; ni < 4; ++ni) {
            bh[ni] = *(const bf16x8*)&sBh[bbase + ni * 640];
            bl[ni] = *(const bf16x8*)&sBl[bbase + ni * 640];
        }
#pragma unroll
        for (int mi = 0; mi < 4; ++mi) {
            const bf16x8 ah = *(const bf16x8*)&sAh[abase + mi * 640];
            const bf16x8 al = *(const bf16x8*)&sAl[abase + mi * 640];
#pragma unroll
            for (int ni = 0; ni < 4; ++ni) {
                acc[mi][ni] = __builtin_amdgcn_mfma_f32_16x16x32_bf16(ah, bh[ni], acc[mi][ni], 0, 0, 0);
                acc[mi][ni] = __builtin_amdgcn_mfma_f32_16x16x32_bf16(ah, bl[ni], acc[mi][ni], 0, 0, 0);
                acc[mi][ni] = __builtin_amdgcn_mfma_f32_16x16x32_bf16(al, bh[ni], acc[mi][ni], 0, 0, 0);
            }
        }
    }

    // ---- epilogue: LDS transpose of MFMA layout, then scores ----
    // MFMA D layout: col = lane&15, row = 4*(lane>>4)+r  (per frag)
    // FULL unroll (compile-time mi) — see scratch-demotion note above.
    float* const sOut = (float*)sMem;                  // 4 waves x [16][68] f32
    float* const sW   = sOut + wave * (16 * 68);
    const int gb = (col0 >> 2) + wc * 16;              // global group base (wave)

#pragma unroll
    for (int mi = 0; mi < 4; ++mi) {
        __syncthreads();
#pragma unroll
        for (int ni = 0; ni < 4; ++ni)
#pragma unroll
            for (int r = 0; r < 4; ++r)
                sW[(kb * 4 + r) * 68 + ni * 16 + fr] = acc[mi][ni][r];
        __syncthreads();

        const int lr    = fr;                          // row 0..15
        const int gq    = kb;                          // group quad 0..3
        const int row_l = wr * 64 + mi * 16 + lr;      // local compact row
        const int cr    = row0 + row_l;
        const int orig  = rid[row_l];
        const float* so = sW + lr * 68 + gq * 16;
        const int g0    = gb + gq * 4;

        float s[4];
#pragma unroll
        for (int j = 0; j < 4; ++j) {
            const int g = g0 + j;
            const float4 lv = *(const float4*)(so + 4 * j);
            const float4 bv = *(const float4*)(bias + 4 * g);
            const float4 uv = *(const float4*)(uu + (size_t)orig * NCOLS + 4 * g);
            s[j] = score_f(lv.x + bv.x, lv.y + bv.y, lv.z + bv.z, lv.w + bv.w, uv);
        }
        *(float4*)&scoresf[(size_t)cr * NGRP + g0] = make_float4(s[0], s[1], s[2], s[3]);
    }
}

// fp32 selection with boundary-gap certification; flags close calls for fp64.
__global__ __launch_bounds__(384)
void select_fast(const float* __restrict__ scoresf, const float* __restrict__ latency,
                 const int* __restrict__ idx, const int* __restrict__ count,
                 float* __restrict__ out, int* __restrict__ ridx, int* __restrict__ rcount)
{
    const int b = blockIdx.x;
    if (b >= *count) return;
    const int t = threadIdx.x;
    const int orig = idx[b];

    __shared__ float sm[NGRP];
    __shared__ float bnd[2];
    __shared__ int   flag;
    const float sg = scoresf[(size_t)b * NGRP + t];
    sm[t] = sg;
    if (t == 0) flag = 0;
    const int budget = budget_of(latency[orig]);   // 1..383 here
    __syncthreads();

    int rank = 0;
#pragma unroll 8
    for (int j = 0; j < NGRP; ++j) {
        const float sj = sm[j];
        rank += (sj > sg || (sj == sg && j < t)) ? 1 : 0;
    }
    if (rank == budget - 1) bnd[0] = sg;   // min of kept set
    if (rank == budget)     bnd[1] = sg;   // max of dropped set
    __syncthreads();
    if (t == 0 && (bnd[0] - bnd[1] < GAP_MIN)) {
        flag = 1;
        ridx[atomicAdd(rcount, 1)] = orig;
    }
    __syncthreads();
    if (flag) return;

    const float keep = (rank < budget) ? 1.0f : 0.0f;
    float* p = out + (size_t)orig * 2048 + 512 + (size_t)(t >> 4) * 64;
    const int h2 = (t & 15) << 1;
    *(float2*)(p + h2)      = make_float2(keep, keep);
    *(float2*)(p + 32 + h2) = make_float2(1.0f - keep, 1.0f - keep);
}

// fp64 repair GEMM over flagged rows only. BM=32 for block-level parallelism.
__global__ __launch_bounds__(256)
void gemm64_repair(const float* __restrict__ x, const float* __restrict__ W,
                   const float* __restrict__ bias, const float* __restrict__ u,
                   const int* __restrict__ ridx, const int* __restrict__ rcount,
                   double* __restrict__ scores)
{
    __shared__ float As[16][36];
    __shared__ float Bs[16][68];
    __shared__ int   rid[32];

    const int cnt  = *rcount;
    const int row0 = blockIdx.y * 32;
    if (row0 >= cnt) return;
    const int col0 = blockIdx.x * 64;
    const int t    = threadIdx.x;

    if (t < 32) rid[t] = ridx[min(row0 + t, cnt - 1)];
    __syncthreads();

    const bool doA = (t < 128);
    const int ar  = t >> 2;            // 0..31 when doA
    const int akc = (t & 3) << 2;
    const int bkr = t >> 4;
    const int bnc = (t & 15) << 2;

    size_t xoff = 0;
    if (doA) xoff = (size_t)rid[ar] * HID + akc;
    const float* wp = W + (size_t)bkr * NCOLS + col0 + bnc;

    const int ty = t >> 4;             // rows 2ty, 2ty+1
    const int tx = t & 15;

    double acc[2][4] = {};

    float4 a0 = make_float4(0, 0, 0, 0);
    if (doA) a0 = *(const float4*)(x + xoff);
    float4 b0 = *(const float4*)(wp);

    for (int k0 = 0; k0 < HID; k0 += 16) {
        __syncthreads();
        if (doA) {
            As[akc + 0][ar] = a0.x; As[akc + 1][ar] = a0.y;
            As[akc + 2][ar] = a0.z; As[akc + 3][ar] = a0.w;
        }
        *(float4*)&Bs[bkr][bnc] = b0;
        __syncthreads();
        if (k0 + 16 < HID) {
            if (doA) a0 = *(const float4*)(x + xoff + k0 + 16);
            b0 = *(const float4*)(wp + (size_t)(k0 + 16) * NCOLS);
        }
#pragma unroll
        for (int k = 0; k < 16; ++k) {
            const double a0d = (double)As[k][ty * 2];
            const double a1d = (double)As[k][ty * 2 + 1];
            const float4 bf  = *(const float4*)&Bs[k][tx * 4];
            const double bd[4] = {(double)bf.x, (double)bf.y, (double)bf.z, (double)bf.w};
#pragma unroll
            for (int j = 0; j < 4; ++j) {
                acc[0][j] = fma(a0d, bd[j], acc[0][j]);
                acc[1][j] = fma(a1d, bd[j], acc[1][j]);
            }
        }
    }

    const int g = (col0 >> 2) + tx;
    const double bs0 = (double)bias[4 * g + 0];
    const double bs1 = (double)bias[4 * g + 1];
    const double bs2 = (double)bias[4 * g + 2];
    const double bs3 = (double)bias[4 * g + 3];
#pragma unroll
    for (int i = 0; i < 2; ++i) {
        const int rl   = ty * 2 + i;
        const int cr   = row0 + rl;
        const int orig = rid[rl];
        const float4 uv = *(const float4*)(u + (size_t)orig * NCOLS + 4 * g);
        const double l0 = acc[i][0] + bs0;
        const double l1 = acc[i][1] + bs1;
        const double l2 = acc[i][2] + bs2;
        const double l3 = acc[i][3] + bs3;
        const double d0 = ((l0 + gumbel_d(uv.x)) - (l1 + gumbel_d(uv.y))) / 5.0;
        const double d1 = ((l2 + gumbel_d(uv.z)) - (l3 + gumbel_d(uv.w))) / 5.0;
        const double p0 = 1.0 / (1.0 + exp(-d0));
        const double p1 = 1.0 / (1.0 + exp(-d1));
        scores[(size_t)cr * NGRP + g] = 0.5 * (p0 + p1);
    }
}

// fp64 selection for flagged rows (no gap test).
__global__ __launch_bounds__(384)
void select_repair(const double* __restrict__ scores, const float* __restrict__ latency,
                   const int* __restrict__ ridx, const int* __restrict__ rcount,
                   float* __restrict__ out)
{
    const int b = blockIdx.x;
    if (b >= *rcount) return;
    const int t = threadIdx.x;
    const int orig = ridx[b];

    __shared__ double sm[NGRP];
    const double sg = scores[(size_t)b * NGRP + t];
    sm[t] = sg;
    const int budget = budget_of(latency[orig]);
    __syncthreads();

    int rank = 0;
#pragma unroll 8
    for (int j = 0; j < NGRP; ++j) {
        const double sj = sm[j];
        rank += (sj > sg || (sj == sg && j < t)) ? 1 : 0;
    }
    const float keep = (rank < budget) ? 1.0f : 0.0f;

    float* p = out + (size_t)orig * 2048 + 512 + (size_t)(t >> 4) * 64;
    const int h2 = (t & 15) << 1;
    *(float2*)(p + h2)      = make_float2(keep, keep);
    *(float2*)(p + 32 + h2) = make_float2(1.0f - keep, 1.0f - keep);
}

extern "C" void kernel_launch(void* const* d_in, const int* in_sizes, int n_in,
                              void* d_out, int out_size, void* d_ws, size_t ws_size,
                              hipStream_t stream) {
    const float* x       = (const float*)d_in[0];
    const float* latency = (const float*)d_in[1];
    const float* W       = (const float*)d_in[2];
    const float* bias    = (const float*)d_in[3];
    const float* u       = (const float*)d_in[4];
    float* out           = (float*)d_out;

    // ws layout (total 50,462,976 B):
    //   [count,rcount.. 256B][idx 64KB][ridx 64KB]
    //   [WT_hi 12.58MB][WT_lo 12.58MB][scoresf 25.17MB]
    //   scores64 (fp64, 50.33MB) ALIASES [WT_hi..scoresf]: WT planes are dead
    //   after gemm_bf16x3, scoresf is dead after select_fast, and gemm64_repair
    //   (which writes scores64) runs after select_fast. Lifetimes disjoint.
    int*    count   = (int*)d_ws;
    int*    rcount  = (int*)((char*)d_ws + 4);
    int*    idx     = (int*)((char*)d_ws + 256);
    int*    ridx    = (int*)((char*)d_ws + 256 + 65536);
    u16*    wt_hi   = (u16*)((char*)d_ws + 131328);
    u16*    wt_lo   = (u16*)((char*)d_ws + 131328 + 12582912);
    float*  scoresf = (float*)((char*)d_ws + 131328 + 25165824);
    double* scores64= (double*)((char*)d_ws + 131328);

    hipMemsetAsync(d_ws, 0, 256, stream);
    convert_w<<<dim3(NCOLS / 32, HID / 32), 256, 0, stream>>>(W, wt_hi, wt_lo);
    prefilter_kernel<<<BATCH, 64, 0, stream>>>(latency, out, count, idx);
    gemm_bf16x3<<<dim3(NCOLS / 128, BATCH / 128), 256, 0, stream>>>(
        x, wt_hi, wt_lo, bias, u, idx, count, scoresf);
    select_fast<<<BATCH, NGRP, 0, stream>>>(scoresf, latency, idx, count, out, ridx, rcount);
    gemm64_repair<<<dim3(NCOLS / 64, BATCH / 32), 256, 0, stream>>>(
        x, W, bias, u, ridx, rcount, scores64);
    select_repair<<<BATCH, NGRP, 0, stream>>>(scores64, latency, ridx, rcount, out);
}

// Round 3
// 1514.014 us; speedup vs baseline: 2.9740x; 1.0936x over previous
//
#include <hip/hip_runtime.h>
#include <math.h>

// Problem constants
#define BATCH  16384
#define HID    4096
#define NCOLS  1536     // NUM_SUB * H * 2
#define NGRP   384      // NUM_SUB * H / RANK

// Gap threshold: bf16x3-path score error vs fp64 is ~2.5e-6 worst case
// (RTZ-hi residual 2^-8 rms -> ~2e-6 logit std; score sens. 0.025; plus fp32
// transcendentals ~1e-6). 2e-5 = 8x margin; validated at this margin ratio.
#define GAP_MIN 2.0e-5f

typedef unsigned short u16;
typedef short bf16x8 __attribute__((ext_vector_type(8)));
typedef float f32x4  __attribute__((ext_vector_type(4)));

__device__ __forceinline__ int budget_of(float lat) {
    float un = rintf(lat * 512.0f);           // round-half-even like jnp.round
    un = fminf(fmaxf(un, 128.0f), 512.0f);
    return (int)un - 128;                     // 0..384
}

__device__ __forceinline__ double gumbel_d(float uu) {
    double v = (double)uu * (1.0 - 2.0e-6) + 1.0e-6;
    return -log(-log(v));
}

// fp32 gumbel, accurate at BOTH tails.
__device__ __forceinline__ float gumbel_f(float u) {
    float inner;
    if (u <= 0.5f) {
        float v = fmaf(u, 0.999998f, 1e-6f);          // u*(1-2e-6)+1e-6
        inner = -logf(v);
    } else {
        float t1 = 1.0f - u;                          // exact
        float w  = fmaf(1e-6f, fmaf(2.0f, u, -1.0f), t1);
        inner = -log1pf(-w);
    }
    return -logf(inner);
}

__device__ __forceinline__ float score_f(float l0, float l1, float l2, float l3,
                                         float4 uv) {
    const float d0 = ((l0 + gumbel_f(uv.x)) - (l1 + gumbel_f(uv.y))) * 0.2f;
    const float d1 = ((l2 + gumbel_f(uv.z)) - (l3 + gumbel_f(uv.w))) * 0.2f;
    const float p0 = 1.0f / (1.0f + expf(-d0));
    const float p1 = 1.0f / (1.0f + expf(-d1));
    return 0.5f * (p0 + p1);
}

// ---- bf16 split helpers ----
__device__ __forceinline__ unsigned bf16_rne_bits(float f) {
    unsigned b = __float_as_uint(f);
    return (b + 0x7FFFu + ((b >> 16) & 1u)) >> 16;
}

// Hot-path split: hi = RTZ-bf16 (bitmask), lo = RNE-bf16(x - hi).
__device__ __forceinline__ void split4(const float4 v, uint2& hi, uint2& lo) {
    const unsigned bx = __float_as_uint(v.x), by = __float_as_uint(v.y),
                   bz = __float_as_uint(v.z), bw = __float_as_uint(v.w);
    const unsigned hx = bx & 0xFFFF0000u, hy = by & 0xFFFF0000u,
                   hz = bz & 0xFFFF0000u, hw = bw & 0xFFFF0000u;
    hi.x = (hx >> 16) | hy;
    hi.y = (hz >> 16) | hw;
    const float lx = v.x - __uint_as_float(hx);
    const float ly = v.y - __uint_as_float(hy);
    const float lz = v.z - __uint_as_float(hz);
    const float lw = v.w - __uint_as_float(hw);
    lo.x = bf16_rne_bits(lx) | (bf16_rne_bits(ly) << 16);
    lo.y = bf16_rne_bits(lz) | (bf16_rne_bits(lw) << 16);
}

// Async global->LDS, 16B per lane. LDS dest is wave-uniform base + lane*16.
__device__ __forceinline__ void gload16(const u16* g, u16* l) {
    __builtin_amdgcn_global_load_lds(
        (const __attribute__((address_space(1))) unsigned int*)g,
        (__attribute__((address_space(3))) unsigned int*)l, 16, 0, 0);
}

// Per-sample classification + trivial-output fill + compaction of interior rows.
__global__ __launch_bounds__(64)
void prefilter_kernel(const float* __restrict__ latency, float* __restrict__ out,
                      int* __restrict__ count, int* __restrict__ idx)
{
    const int b = blockIdx.x;
    const int t = threadIdx.x;
    const int budget = budget_of(latency[b]);
    float* obase = out + (size_t)b * 2048;

    const float4 ones = make_float4(1.f, 1.f, 1.f, 1.f);
    ((float4*)obase)[t]      = ones;   // prefix: layers 0..7 all ones
    ((float4*)obase)[t + 64] = ones;

    if (budget > 0 && budget < NGRP) {
        if (t == 0) { int s = atomicAdd(count, 1); idx[s] = b; }
    } else {
        const float K = (budget == 0) ? 0.0f : 1.0f;
#pragma unroll
        for (int j = 0; j < 6; ++j) {
            const int i = j * 64 + t;
            const int p = i * 4;             // p = l*64 + s*32 + h
            const int s = (p >> 5) & 1;
            const float v = s ? (1.0f - K) : K;
            ((float4*)(obase + 512))[i] = make_float4(v, v, v, v);
        }
    }
}

// One-time W transpose + bf16 hi/lo split into a kb-major TILED layout:
//   wt[colblk 12][ktile 128][kb 4][n 128][e 8]  (u16)
// so GEMM B-staging is a LINEAR, fully-coalesced global_load_lds and the
// LDS image [kb][n][8] gives conflict-free ds_read_b128 fragments.
__global__ __launch_bounds__(256)
void convert_w(const float* __restrict__ W, u16* __restrict__ wt_hi,
               u16* __restrict__ wt_lo)
{
    __shared__ float sT[32][33];
    const int n0 = blockIdx.x * 32, k0 = blockIdx.y * 32;
    const int t  = threadIdx.x;
    {
        const int lr = t >> 3, lc = (t & 7) * 4;
        const float4 v = *(const float4*)(W + (size_t)(k0 + lr) * NCOLS + n0 + lc);
        sT[lr][lc] = v.x; sT[lr][lc + 1] = v.y; sT[lr][lc + 2] = v.z; sT[lr][lc + 3] = v.w;
    }
    __syncthreads();
    const int ln = t >> 3, lk = (t & 7) * 4;     // ln: n-local, lk: k-local
    unsigned hb[4], lb[4];
#pragma unroll
    for (int j = 0; j < 4; ++j) {
        const float xv = sT[lk + j][ln];
        const unsigned h = bf16_rne_bits(xv);          // RNE hi for W (one-time)
        const float hf = __uint_as_float(h << 16);
        hb[j] = h;
        lb[j] = bf16_rne_bits(xv - hf);
    }
    uint2 hw, lw;
    hw.x = hb[0] | (hb[1] << 16); hw.y = hb[2] | (hb[3] << 16);
    lw.x = lb[0] | (lb[1] << 16); lw.y = lb[2] | (lb[3] << 16);
    const int gn = n0 + ln;
    const size_t off = ((size_t)((gn >> 7) * 128 + (k0 >> 5)) * 4 + (lk >> 3)) * 1024
                     + (size_t)(gn & 127) * 8 + (lk & 7);
    *(uint2*)(wt_hi + off) = hw;
    *(uint2*)(wt_lo + off) = lw;
}

// bf16x3 MFMA GEMM (128x128 tile, BK=32) + fp32 gumbel-softmax scores.
// acc = x_hi@w_hi + x_hi@w_lo + x_lo@w_hi, fp32 accumulation on matrix cores.
// B is staged with global_load_lds (width 16) from the pre-tiled wt planes;
// A is fp32->bf16 split in-kernel (register prefetch, uint4 LDS writes).
// NOTE: every access to acc[][] must be compile-time-indexed (full unroll) —
// a single runtime index demotes the whole array to scratch (r1 post-mortem).
__global__ __launch_bounds__(256)
void gemm_bf16x3(const float* __restrict__ x, const u16* __restrict__ wt_hi,
                 const u16* __restrict__ wt_lo, const float* __restrict__ bias,
                 const float* __restrict__ uu, const int* __restrict__ idx,
                 const int* __restrict__ count, float* __restrict__ scoresf)
{
    // A planes: [128][40] u16 (pad->80B rows, 2-way banks = free)
    // B planes: [4 kb][128 n][8 e] u16 linear (gload_lds dest; reads 2-way free)
    __shared__ __align__(16) u16 sMem[2 * 5120 + 2 * 4096];   // 36864 B
    __shared__ int rid[128];
    u16* const sAh = sMem;
    u16* const sAl = sMem + 5120;
    u16* const sBh = sMem + 10240;
    u16* const sBl = sMem + 14336;

    const int cnt  = *count;
    const int row0 = blockIdx.y * 128;
    if (row0 >= cnt) return;
    const int cb   = blockIdx.x;
    const int col0 = cb * 128;
    const int t    = threadIdx.x;

    if (t < 128) rid[t] = idx[min(row0 + t, cnt - 1)];
    __syncthreads();

    // ---- A staging maps ----
    const int ar  = t >> 2;             // A rows ar and ar+64
    const int akc = (t & 3) << 3;       // k offset {0,8,16,24}
    const int arow  = ar * 40 + akc;
    const int arow2 = (ar + 64) * 40 + akc;
    const size_t xoff0 = (size_t)rid[ar] * HID + akc;
    const size_t xoff1 = (size_t)rid[ar + 64] * HID + akc;

    // ---- B staging (global_load_lds) ----
    const int wave = t >> 6;
    const size_t bsrc0 = (size_t)cb * 524288 + (size_t)t * 8;  // + kt*4096
    const int ldsB0 = wave * 512;          // issue 0 wave base (u16 units)
    const int ldsB1 = 2048 + wave * 512;   // issue 1

    // ---- fragment maps ----
    const int lane = t & 63;
    const int wr = wave >> 1;           // wave row half
    const int wc = wave & 1;            // wave col half
    const int fr = lane & 15;
    const int kb = lane >> 4;           // 0..3
    const int abase = (wr * 64 + fr) * 40 + kb * 8;
    const int bfrag = kb * 1024 + (wc * 64 + fr) * 8;   // + ni*128

    f32x4 acc[4][4] = {};

    // prefetch A tile 0
    float4 a00 = *(const float4*)(x + xoff0);
    float4 a01 = *(const float4*)(x + xoff0 + 4);
    float4 a10 = *(const float4*)(x + xoff1);
    float4 a11 = *(const float4*)(x + xoff1 + 4);

#pragma unroll 1
    for (int k0 = 0; k0 < HID; k0 += 32) {
        __syncthreads();
        {   // A: convert fp32 -> bf16 hi/lo, combined 16B LDS writes
            uint2 h0, l0, h1, l1;
            split4(a00, h0, l0); split4(a01, h1, l1);
            *(uint4*)&sAh[arow]  = make_uint4(h0.x, h0.y, h1.x, h1.y);
            *(uint4*)&sAl[arow]  = make_uint4(l0.x, l0.y, l1.x, l1.y);
            split4(a10, h0, l0); split4(a11, h1, l1);
            *(uint4*)&sAh[arow2] = make_uint4(h0.x, h0.y, h1.x, h1.y);
            *(uint4*)&sAl[arow2] = make_uint4(l0.x, l0.y, l1.x, l1.y);
        }
        {   // B: async direct-to-LDS, current K-tile (linear, coalesced)
            const size_t bs = bsrc0 + (size_t)(k0 >> 5) * 4096;
            gload16(wt_hi + bs,        sBh + ldsB0);
            gload16(wt_hi + bs + 2048, sBh + ldsB1);
            gload16(wt_lo + bs,        sBl + ldsB0);
            gload16(wt_lo + bs + 2048, sBl + ldsB1);
        }
        __syncthreads();   // drains vmcnt (gload_lds) + lgkm (A writes)

        if (k0 + 32 < HID) {
            a00 = *(const float4*)(x + xoff0 + k0 + 32);
            a01 = *(const float4*)(x + xoff0 + k0 + 36);
            a10 = *(const float4*)(x + xoff1 + k0 + 32);
            a11 = *(const float4*)(x + xoff1 + k0 + 36);
        }

        bf16x8 bh[4], bl[4];
#pragma unroll
        for (int ni = 0; ni < 4; ++ni) {
            bh[ni] = *(const bf16x8*)&sBh[bfrag + ni * 128];
            bl[ni] = *(const bf16x8*)&sBl[bfrag + ni * 128];
        }
#pragma unroll
        for (int mi = 0; mi < 4; ++mi) {
            const bf16x8 ah = *(const bf16x8*)&sAh[abase + mi * 640];
            const bf16x8 al = *(const bf16x8*)&sAl[abase + mi * 640];
#pragma unroll
            for (int ni = 0; ni < 4; ++ni) {
                acc[mi][ni] = __builtin_amdgcn_mfma_f32_16x16x32_bf16(ah, bh[ni], acc[mi][ni], 0, 0, 0);
                acc[mi][ni] = __builtin_amdgcn_mfma_f32_16x16x32_bf16(ah, bl[ni], acc[mi][ni], 0, 0, 0);
                acc[mi][ni] = __builtin_amdgcn_mfma_f32_16x16x32_bf16(al, bh[ni], acc[mi][ni], 0, 0, 0);
            }
        }
    }

    // ---- epilogue: LDS transpose of MFMA layout, then scores ----
    // MFMA D layout: col = lane&15, row = 4*(lane>>4)+r  (per frag)
    // FULL unroll (compile-time mi) — see scratch-demotion note above.
    float* const sOut = (float*)sMem;                  // 4 waves x [16][68] f32
    float* const sW   = sOut + wave * (16 * 68);
    const int gb = (col0 >> 2) + wc * 16;              // global group base (wave)

#pragma unroll
    for (int mi = 0; mi < 4; ++mi) {
        __syncthreads();
#pragma unroll
        for (int ni = 0; ni < 4; ++ni)
#pragma unroll
            for (int r = 0; r < 4; ++r)
                sW[(kb * 4 + r) * 68 + ni * 16 + fr] = acc[mi][ni][r];
        __syncthreads();

        const int lr    = fr;                          // row 0..15
        const int gq    = kb;                          // group quad 0..3
        const int row_l = wr * 64 + mi * 16 + lr;      // local compact row
        const int cr    = row0 + row_l;
        const int orig  = rid[row_l];
        const float* so = sW + lr * 68 + gq * 16;
        const int g0    = gb + gq * 4;

        float s[4];
#pragma unroll
        for (int j = 0; j < 4; ++j) {
            const int g = g0 + j;
            const float4 lv = *(const float4*)(so + 4 * j);
            const float4 bv = *(const float4*)(bias + 4 * g);
            const float4 uv = *(const float4*)(uu + (size_t)orig * NCOLS + 4 * g);
            s[j] = score_f(lv.x + bv.x, lv.y + bv.y, lv.z + bv.z, lv.w + bv.w, uv);
        }
        *(float4*)&scoresf[(size_t)cr * NGRP + g0] = make_float4(s[0], s[1], s[2], s[3]);
    }
}

// fp32 selection with boundary-gap certification; flags close calls for fp64.
__global__ __launch_bounds__(384)
void select_fast(const float* __restrict__ scoresf, const float* __restrict__ latency,
                 const int* __restrict__ idx, const int* __restrict__ count,
                 float* __restrict__ out, int* __restrict__ ridx, int* __restrict__ rcount)
{
    const int b = blockIdx.x;
    if (b >= *count) return;
    const int t = threadIdx.x;
    const int orig = idx[b];

    __shared__ float sm[NGRP];
    __shared__ float bnd[2];
    __shared__ int   flag;
    const float sg = scoresf[(size_t)b * NGRP + t];
    sm[t] = sg;
    if (t == 0) flag = 0;
    const int budget = budget_of(latency[orig]);   // 1..383 here
    __syncthreads();

    int rank = 0;
#pragma unroll 8
    for (int j = 0; j < NGRP; ++j) {
        const float sj = sm[j];
        rank += (sj > sg || (sj == sg && j < t)) ? 1 : 0;
    }
    if (rank == budget - 1) bnd[0] = sg;   // min of kept set
    if (rank == budget)     bnd[1] = sg;   // max of dropped set
    __syncthreads();
    if (t == 0 && (bnd[0] - bnd[1] < GAP_MIN)) {
        flag = 1;
        ridx[atomicAdd(rcount, 1)] = orig;
    }
    __syncthreads();
    if (flag) return;

    const float keep = (rank < budget) ? 1.0f : 0.0f;
    float* p = out + (size_t)orig * 2048 + 512 + (size_t)(t >> 4) * 64;
    const int h2 = (t & 15) << 1;
    *(float2*)(p + h2)      = make_float2(keep, keep);
    *(float2*)(p + 32 + h2) = make_float2(1.0f - keep, 1.0f - keep);
}

// fp64 repair GEMM over flagged rows only. BM=32 for block-level parallelism.
__global__ __launch_bounds__(256)
void gemm64_repair(const float* __restrict__ x, const float* __restrict__ W,
                   const float* __restrict__ bias, const float* __restrict__ u,
                   const int* __restrict__ ridx, const int* __restrict__ rcount,
                   double* __restrict__ scores)
{
    __shared__ float As[16][36];
    __shared__ float Bs[16][68];
    __shared__ int   rid[32];

    const int cnt  = *rcount;
    const int row0 = blockIdx.y * 32;
    if (row0 >= cnt) return;
    const int col0 = blockIdx.x * 64;
    const int t    = threadIdx.x;

    if (t < 32) rid[t] = ridx[min(row0 + t, cnt - 1)];
    __syncthreads();

    const bool doA = (t < 128);
    const int ar  = t >> 2;            // 0..31 when doA
    const int akc = (t & 3) << 2;
    const int bkr = t >> 4;
    const int bnc = (t & 15) << 2;

    size_t xoff = 0;
    if (doA) xoff = (size_t)rid[ar] * HID + akc;
    const float* wp = W + (size_t)bkr * NCOLS + col0 + bnc;

    const int ty = t >> 4;             // rows 2ty, 2ty+1
    const int tx = t & 15;

    double acc[2][4] = {};

    float4 a0 = make_float4(0, 0, 0, 0);
    if (doA) a0 = *(const float4*)(x + xoff);
    float4 b0 = *(const float4*)(wp);

    for (int k0 = 0; k0 < HID; k0 += 16) {
        __syncthreads();
        if (doA) {
            As[akc + 0][ar] = a0.x; As[akc + 1][ar] = a0.y;
            As[akc + 2][ar] = a0.z; As[akc + 3][ar] = a0.w;
        }
        *(float4*)&Bs[bkr][bnc] = b0;
        __syncthreads();
        if (k0 + 16 < HID) {
            if (doA) a0 = *(const float4*)(x + xoff + k0 + 16);
            b0 = *(const float4*)(wp + (size_t)(k0 + 16) * NCOLS);
        }
#pragma unroll
        for (int k = 0; k < 16; ++k) {
            const double a0d = (double)As[k][ty * 2];
            const double a1d = (double)As[k][ty * 2 + 1];
            const float4 bf  = *(const float4*)&Bs[k][tx * 4];
            const double bd[4] = {(double)bf.x, (double)bf.y, (double)bf.z, (double)bf.w};
#pragma unroll
            for (int j = 0; j < 4; ++j) {
                acc[0][j] = fma(a0d, bd[j], acc[0][j]);
                acc[1][j] = fma(a1d, bd[j], acc[1][j]);
            }
        }
    }

    const int g = (col0 >> 2) + tx;
    const double bs0 = (double)bias[4 * g + 0];
    const double bs1 = (double)bias[4 * g + 1];
    const double bs2 = (double)bias[4 * g + 2];
    const double bs3 = (double)bias[4 * g + 3];
#pragma unroll
    for (int i = 0; i < 2; ++i) {
        const int rl   = ty * 2 + i;
        const int cr   = row0 + rl;
        const int orig = rid[rl];
        const float4 uv = *(const float4*)(u + (size_t)orig * NCOLS + 4 * g);
        const double l0 = acc[i][0] + bs0;
        const double l1 = acc[i][1] + bs1;
        const double l2 = acc[i][2] + bs2;
        const double l3 = acc[i][3] + bs3;
        const double d0 = ((l0 + gumbel_d(uv.x)) - (l1 + gumbel_d(uv.y))) / 5.0;
        const double d1 = ((l2 + gumbel_d(uv.z)) - (l3 + gumbel_d(uv.w))) / 5.0;
        const double p0 = 1.0 / (1.0 + exp(-d0));
        const double p1 = 1.0 / (1.0 + exp(-d1));
        scores[(size_t)cr * NGRP + g] = 0.5 * (p0 + p1);
    }
}

// fp64 selection for flagged rows (no gap test).
__global__ __launch_bounds__(384)
void select_repair(const double* __restrict__ scores, const float* __restrict__ latency,
                   const int* __restrict__ ridx, const int* __restrict__ rcount,
                   float* __restrict__ out)
{
    const int b = blockIdx.x;
    if (b >= *rcount) return;
    const int t = threadIdx.x;
    const int orig = ridx[b];

    __shared__ double sm[NGRP];
    const double sg = scores[(size_t)b * NGRP + t];
    sm[t] = sg;
    const int budget = budget_of(latency[orig]);
    __syncthreads();

    int rank = 0;
#pragma unroll 8
    for (int j = 0; j < NGRP; ++j) {
        const double sj = sm[j];
        rank += (sj > sg || (sj == sg && j < t)) ? 1 : 0;
    }
    const float keep = (rank < budget) ? 1.0f : 0.0f;

    float* p = out + (size_t)orig * 2048 + 512 + (size_t)(t >> 4) * 64;
    const int h2 = (t & 15) << 1;
    *(float2*)(p + h2)      = make_float2(keep, keep);
    *(float2*)(p + 32 + h2) = make_float2(1.0f - keep, 1.0f - keep);
}

extern "C" void kernel_launch(void* const* d_in, const int* in_sizes, int n_in,
                              void* d_out, int out_size, void* d_ws, size_t ws_size,
                              hipStream_t stream) {
    const float* x       = (const float*)d_in[0];
    const float* latency = (const float*)d_in[1];
    const float* W       = (const float*)d_in[2];
    const float* bias    = (const float*)d_in[3];
    const float* u       = (const float*)d_in[4];
    float* out           = (float*)d_out;

    // ws layout (total 50,462,976 B):
    //   [count,rcount.. 256B][idx 64KB][ridx 64KB]
    //   [WT_hi 12.58MB][WT_lo 12.58MB][scoresf 25.17MB]
    //   scores64 (fp64, 50.33MB) ALIASES [WT_hi..scoresf]: WT planes are dead
    //   after gemm_bf16x3, scoresf is dead after select_fast, and gemm64_repair
    //   (which writes scores64) runs after select_fast. Lifetimes disjoint.
    int*    count   = (int*)d_ws;
    int*    rcount  = (int*)((char*)d_ws + 4);
    int*    idx     = (int*)((char*)d_ws + 256);
    int*    ridx    = (int*)((char*)d_ws + 256 + 65536);
    u16*    wt_hi   = (u16*)((char*)d_ws + 131328);
    u16*    wt_lo   = (u16*)((char*)d_ws + 131328 + 12582912);
    float*  scoresf = (float*)((char*)d_ws + 131328 + 25165824);
    double* scores64= (double*)((char*)d_ws + 131328);

    hipMemsetAsync(d_ws, 0, 256, stream);
    convert_w<<<dim3(NCOLS / 32, HID / 32), 256, 0, stream>>>(W, wt_hi, wt_lo);
    prefilter_kernel<<<BATCH, 64, 0, stream>>>(latency, out, count, idx);
    gemm_bf16x3<<<dim3(NCOLS / 128, BATCH / 128), 256, 0, stream>>>(
        x, wt_hi, wt_lo, bias, u, idx, count, scoresf);
    select_fast<<<BATCH, NGRP, 0, stream>>>(scoresf, latency, idx, count, out, ridx, rcount);
    gemm64_repair<<<dim3(NCOLS / 64, BATCH / 32), 256, 0, stream>>>(
        x, W, bias, u, ridx, rcount, scores64);
    select_repair<<<BATCH, NGRP, 0, stream>>>(scores64, latency, ridx, rcount, out);
}